// Round 12
// baseline (367.743 us; speedup 1.0000x reference)
//
#include <hip/hip_runtime.h>
#include <math.h>

// SparseCoding, round 12.
// vs R11 (325 us; R10 best 312): kernel is LATENCY-bound at 2 waves/SIMD
// (R11: issue count down 20%, wall flat). Double occupancy:
//  - 1024-thread blocks (16 waves), 4 blocks/window (8 rows), 16-way K-split.
//    G fragment 16 K-rows x 4 cols = 64 VGPRs/thread -> ~100 total ->
//    __launch_bounds__(1024,4) = 4 waves/SIMD (was 2).
//  - single 128 KB exchange buffer (dual no longer fits) -> 2 barriers/iter
//    (R4/R6 showed barrier count is cheap). s_xn aliases exchange head.
//  - coef ownership 2/lane (cf[0],cf[1]); readlane-from-register GEMM kept.
//  - exchange gather at +4b rotation to keep bank conflicts ~2-way.
//  - lag-2 convergence consume, last-man-out post, 4 arrivals/window kept.
#define NB     256
#define NF     128
#define FT     1024
#define NW     63
#define TORIG  256
#define MAXIT  48
#define RPB    8       // rows per block
#define NBLK   4       // blocks per window
#define GRID   256     // XCD-swizzled; 4 blocks decode w==63: gram+exit

typedef float f2 __attribute__((ext_vector_type(2)));
__device__ __forceinline__ f2 pkfma(f2 a, f2 b, f2 c) {
    return __builtin_elementwise_fma(a, b, c);
}
__device__ __forceinline__ float rl(float v, int lane) {
    return __uint_as_float((unsigned)__builtin_amdgcn_readlane((int)__float_as_uint(v), lane));
}

__global__ __launch_bounds__(1024, 4) void window_kernel(
    const float* __restrict__ spec,
    const float* __restrict__ basis,
    float* __restrict__ G,               // ws: 256x256
    const int* __restrict__ p_niter,
    const int* __restrict__ p_pad,
    const int* __restrict__ p_stride,
    double* __restrict__ sxbuf,          // [NW][NBLK]
    double* __restrict__ gpart,          // [MAXIT][NW][NBLK][2]
    unsigned int* __restrict__ gcnt,     // [MAXIT*NW] arrivals + [MAXIT*NW]=gbar (memset 0)
    float* __restrict__ out)             // (32,256,63)
{
    __shared__ float  s_ex[16 * RPB * 256];    // 128 KB exchange; head aliases s_xn
    __shared__ float  s_gred[4][NB];           // 4 KB gram j-reduce
    __shared__ float  s_mnh[16], s_mxh[16];
    __shared__ float  s_mn[RPB], s_rng[RPB];
    __shared__ double s_dred[16];
    __shared__ float  s_redq[16], s_redr[16];
    __shared__ unsigned int s_wcnt;
    __shared__ int    s_stop[2];
    float* const s_xn = s_ex;                  // 8*1024 floats (32 KB), setup only

    const int bid = blockIdx.x;
    const int yy  = bid >> 3;
    const int q   = yy & 3;
    const int w   = (bid & 7) + 8 * (yy >> 2);   // 4 blocks/window share bid%8 (XCD)
    const int tid = threadIdx.x;
    const int kh  = tid >> 6;                    // wave 0..15: K-slice [16kh,16kh+16)
    const int kg  = tid & 63;
    const int bo  = kg >> 3;                     // owned local row
    const int jo  = kg & 7;                      // owned k-pair: ko = 16kh+2jo (+0,+1)
    const int ko  = 16 * kh + 2 * jo;
    const int n_iter = p_niter[0];
    const int t0     = w * p_stride[0] - p_pad[0];
    unsigned int* gbar = gcnt + MAXIT * NW;

    // ================= fused Gram: block bid computes G row bid ==================
    {
        const int c = tid & 255, jh = tid >> 8;  // 4-way j split
        float acc = 0.f;
        const float* bp = basis + (size_t)(jh * 256) * NB;
        #pragma unroll 16
        for (int j = 0; j < 256; ++j)
            acc = fmaf(bp[j * NB + bid], bp[j * NB + c], acc);
        s_gred[jh][c] = acc;
        __syncthreads();
        if (jh == 0)
            G[(size_t)bid * NB + c] = (s_gred[0][c] + s_gred[1][c])
                                    + (s_gred[2][c] + s_gred[3][c]);
    }
    __threadfence();
    __syncthreads();
    if (tid == 0) atomicAdd(gbar, 1u);
    if (w >= NW) return;

    // ================= stage raw window (8 rows x 1024) ==========================
    #pragma unroll
    for (int i = 0; i < 8; ++i) {
        const int jj = tid;                      // row i, col tid
        const int f = jj >> 3, t = jj & 7, tq = t0 + t;
        s_xn[i * FT + jj] = (tq >= 0 && tq < TORIG)
            ? spec[((size_t)(q * RPB + i) * NF + f) * TORIG + tq] : 0.f;
    }
    __syncthreads();
    {   // min/max: wave kh scans half (kh&1) of row kh>>1
        const int rr = kh >> 1, hh = kh & 1;
        float mn = __builtin_inff(), mx = -__builtin_inff();
        #pragma unroll
        for (int i = 0; i < 8; ++i) {
            const float v = s_xn[rr * FT + hh * 512 + i * 64 + kg];
            mn = fminf(mn, v); mx = fmaxf(mx, v);
        }
        #pragma unroll
        for (int off = 32; off; off >>= 1) {
            mn = fminf(mn, __shfl_down(mn, off));
            mx = fmaxf(mx, __shfl_down(mx, off));
        }
        if (kg == 0) { s_mnh[kh] = mn; s_mxh[kh] = mx; }
    }
    __syncthreads();
    if (tid < RPB) {
        const float mn = fminf(s_mnh[2 * tid], s_mnh[2 * tid + 1]);
        const float mx = fmaxf(s_mxh[2 * tid], s_mxh[2 * tid + 1]);
        s_mn[tid] = mn; s_rng[tid] = mx - mn;
    }
    __syncthreads();
    double sx2p = 0.0;
    #pragma unroll
    for (int i = 0; i < 8; ++i) {
        const float v = (s_xn[i * FT + tid] - s_mn[i]) / s_rng[i];   // exact div
        s_xn[i * FT + tid] = v;
        sx2p += (double)v * (double)v;
    }
    #pragma unroll
    for (int off = 32; off; off >>= 1) sx2p += __shfl_down(sx2p, off);
    if (kg == 0) s_dred[kh] = sx2p;
    __syncthreads();
    if (tid == 0) {
        double s = 0.0;
        #pragma unroll
        for (int i = 0; i < 16; ++i) s += s_dred[i];
        sxbuf[w * NBLK + q] = s;
        __threadfence();
    }

    // ================= xB = xnorm @ basis: wave kh does j in [64kh,64kh+64) ======
    f2 xb01[RPB], xb23[RPB];
    #pragma unroll
    for (int b = 0; b < RPB; ++b) { xb01[b] = (f2){0.f, 0.f}; xb23[b] = (f2){0.f, 0.f}; }
    for (int i0 = 0; i0 < 64; i0 += 4) {
        const int jj = kh * 64 + i0;
        float4 bv[4];
        #pragma unroll
        for (int t = 0; t < 4; ++t)
            bv[t] = *(const float4*)(basis + (size_t)(jj + t) * NB + 4 * kg);
        #pragma unroll
        for (int b = 0; b < RPB; ++b) {
            const float4 x4 = *(const float4*)&s_xn[b * FT + jj];
            const f2 vx = {x4.x, x4.x}, vy = {x4.y, x4.y};
            const f2 vz = {x4.z, x4.z}, vw = {x4.w, x4.w};
            xb01[b] = pkfma(vx, (f2){bv[0].x, bv[0].y}, xb01[b]);
            xb23[b] = pkfma(vx, (f2){bv[0].z, bv[0].w}, xb23[b]);
            xb01[b] = pkfma(vy, (f2){bv[1].x, bv[1].y}, xb01[b]);
            xb23[b] = pkfma(vy, (f2){bv[1].z, bv[1].w}, xb23[b]);
            xb01[b] = pkfma(vz, (f2){bv[2].x, bv[2].y}, xb01[b]);
            xb23[b] = pkfma(vz, (f2){bv[2].z, bv[2].w}, xb23[b]);
            xb01[b] = pkfma(vw, (f2){bv[3].x, bv[3].y}, xb01[b]);
            xb23[b] = pkfma(vw, (f2){bv[3].z, bv[3].w}, xb23[b]);
        }
    }
    __syncthreads();               // all s_xn reads done; safe to overwrite exchange
    #pragma unroll
    for (int b = 0; b < RPB; ++b)
        *(float4*)&s_ex[(kh * RPB + b) * 256 + ((4 * kg + 4 * b) & 255)] =
            make_float4(xb01[b].x, xb01[b].y, xb23[b].x, xb23[b].y);
    __syncthreads();
    f2 xB = {0.f, 0.f};            // owned (row bo, cols ko, ko+1)
    #pragma unroll
    for (int k2 = 0; k2 < 16; ++k2)
        xB += *(const f2*)&s_ex[(k2 * RPB + bo) * 256 + ((ko + 4 * bo) & 255)];

    // ================= wait for G, load register fragment ========================
    if (tid == 0) {
        while (__hip_atomic_load(gbar, __ATOMIC_ACQUIRE, __HIP_MEMORY_SCOPE_AGENT) < (unsigned)GRID)
            __builtin_amdgcn_s_sleep(1);
    }
    if (tid == 64) { s_wcnt = 0; s_stop[0] = 0; s_stop[1] = 0; }
    __syncthreads();
    float4 g[16];                  // G[16kh+kl][4kg..4kg+3]
    #pragma unroll
    for (int kl = 0; kl < 16; ++kl)
        g[kl] = *(const float4*)(G + (size_t)(16 * kh + kl) * NB + 4 * kg);

    // ================= init owned coef / Adam (2 coefs/thread) ===================
    const float C0 = 0.5f / 256.f;
    float cf[2]  = {C0, C0}, cfp[2] = {C0, C0};
    float m_[2]  = {0, 0},   v_[2]  = {0, 0};
    float b1p = 1.f, b2p = 1.f;
    float old_loss = 1e-10f;      // tid64 only
    double sxtot = 0.0;           // tid64 only
    const float c1 = 2.f / 32768.f, c2 = 0.2f / 8192.f;
    int use_prev = 0;

    for (int it = 0; it < n_iter; ++it) {
        const int p = it & 1;

        // ---- tid64: LAG-2 consume (totals posted ~1.5 iterations ago) ----
        if (tid == 64 && it >= 2) {
            const int itc = it - 2;
            while (__hip_atomic_load(&gcnt[itc * NW + w], __ATOMIC_ACQUIRE,
                                     __HIP_MEMORY_SCOPE_AGENT) < (unsigned)NBLK)
                __builtin_amdgcn_s_sleep(1);
            const size_t pbm = ((size_t)itc * NW + w) * NBLK;
            double Qt = 0.0, Rt = 0.0;
            #pragma unroll
            for (int i = 0; i < NBLK; ++i) {
                Qt += gpart[(pbm + i) * 2 + 0];
                Rt += gpart[(pbm + i) * 2 + 1];
            }
            if (itc == 0)
                sxtot = sxbuf[w * NBLK + 0] + sxbuf[w * NBLK + 1] +
                        sxbuf[w * NBLK + 2] + sxbuf[w * NBLK + 3];
            const float loss = (float)((Qt + sxtot) / 32768.0 + 0.2 * (Rt / 8192.0));
            const float stat = fabsf(old_loss - loss) / old_loss;
            old_loss = loss;
            s_stop[p] = (stat < 1e-3f) ? 1 : 0;
        }

        // ---- GEMM (packed), b outer, write-as-you-go; K-slice [16kh,16kh+16) ----
        #pragma unroll
        for (int b = 0; b < RPB; ++b) {
            f2 a01 = {0.f, 0.f}, a23 = {0.f, 0.f};
            #pragma unroll
            for (int j = 0; j < 8; ++j) {
                const int L = b * 8 + j;      // lane owning coef[b][16kh+2j(+1)]
                const float s0 = rl(cf[0], L), s1 = rl(cf[1], L);
                const float4 g0 = g[2 * j], g1 = g[2 * j + 1];
                const f2 v0 = {s0, s0}, v1 = {s1, s1};
                a01 = pkfma(v0, (f2){g0.x, g0.y}, a01);
                a23 = pkfma(v0, (f2){g0.z, g0.w}, a23);
                a01 = pkfma(v1, (f2){g1.x, g1.y}, a01);
                a23 = pkfma(v1, (f2){g1.z, g1.w}, a23);
            }
            *(float4*)&s_ex[(kh * RPB + b) * 256 + ((4 * kg + 4 * b) & 255)] =
                make_float4(a01.x, a01.y, a23.x, a23.y);
        }

        __syncthreads();          // B1: exchange + s_stop[p] visible

        if (s_stop[p]) { use_prev = 1; break; }   // t*=it-2 -> answer = cfp

        // ---- K-reduce at owned coords (16 slices, float2) ----
        f2 aa = {0.f, 0.f};
        #pragma unroll
        for (int k2 = 0; k2 < 16; ++k2)
            aa += *(const f2*)&s_ex[(k2 * RPB + bo) * 256 + ((ko + 4 * bo) & 255)];

        // ---- loss partials + last-man-out block post (skip on final iter) ----
        if (it + 1 < n_iter) {
            float qc = cf[0] * (aa.x - 2.f * xB.x) + cf[1] * (aa.y - 2.f * xB.y);
            float rr = fabsf(cf[0]) + fabsf(cf[1]);
            #pragma unroll
            for (int off = 32; off; off >>= 1) {
                qc += __shfl_down(qc, off);
                rr += __shfl_down(rr, off);
            }
            if (kg == 0) {
                s_redq[kh] = qc; s_redr[kh] = rr;
                __threadfence_block();
                const unsigned old = __hip_atomic_fetch_add(&s_wcnt, 1u,
                                        __ATOMIC_ACQ_REL, __HIP_MEMORY_SCOPE_WORKGROUP);
                if (old == 15u) {     // last wave: fixed-order sum + post
                    float Q = 0.f, R = 0.f;
                    #pragma unroll
                    for (int i = 0; i < 16; ++i) { Q += s_redq[i]; R += s_redr[i]; }
                    s_wcnt = 0u;
                    const size_t pb = ((size_t)it * NW + w) * NBLK;
                    gpart[(pb + q) * 2 + 0] = (double)Q;
                    gpart[(pb + q) * 2 + 1] = (double)R;
                    __hip_atomic_fetch_add(&gcnt[it * NW + w], 1u,
                                           __ATOMIC_RELEASE, __HIP_MEMORY_SCOPE_AGENT);
                }
            }
        }

        // ---- Adam update on 2 owned coefs (fast rcp/sqrt) ----
        b1p *= 0.9f; b2p *= 0.999f;
        const float rb1 = __builtin_amdgcn_rcpf(1.f - b1p);
        const float rb2 = __builtin_amdgcn_rcpf(1.f - b2p);
        const float av[2] = {aa.x, aa.y};
        const float xv[2] = {xB.x, xB.y};
        #pragma unroll
        for (int j = 0; j < 2; ++j) {
            const float c_ = cf[j];
            cfp[j] = c_;
            const float sgn = (c_ > 0.f) ? 1.f : ((c_ < 0.f) ? -1.f : 0.f);
            const float gg = c1 * (av[j] - xv[j]) + c2 * sgn;
            m_[j] = 0.9f * m_[j] + 0.1f * gg;
            v_[j] = 0.999f * v_[j] + 0.001f * gg * gg;
            const float den = __builtin_amdgcn_sqrtf(v_[j] * rb2) + 1e-8f;
            cf[j] = c_ - 1e-3f * (m_[j] * rb1) * __builtin_amdgcn_rcpf(den);
        }

        __syncthreads();          // B2: exchange reads done before next-iter writes
    }

    // ---- post-loop consume round: conv at t = n_iter-2 (if not already stopped) ----
    if (!use_prev && n_iter >= 2) {
        if (tid == 64) {
            const int itc = n_iter - 2;
            while (__hip_atomic_load(&gcnt[itc * NW + w], __ATOMIC_ACQUIRE,
                                     __HIP_MEMORY_SCOPE_AGENT) < (unsigned)NBLK)
                __builtin_amdgcn_s_sleep(1);
            const size_t pbm = ((size_t)itc * NW + w) * NBLK;
            double Qt = 0.0, Rt = 0.0;
            #pragma unroll
            for (int i = 0; i < NBLK; ++i) {
                Qt += gpart[(pbm + i) * 2 + 0];
                Rt += gpart[(pbm + i) * 2 + 1];
            }
            if (itc == 0)
                sxtot = sxbuf[w * NBLK + 0] + sxbuf[w * NBLK + 1] +
                        sxbuf[w * NBLK + 2] + sxbuf[w * NBLK + 3];
            const float loss = (float)((Qt + sxtot) / 32768.0 + 0.2 * (Rt / 8192.0));
            const float stat = fabsf(old_loss - loss) / old_loss;
            s_stop[0] = (stat < 1e-3f) ? 1 : 0;
        }
        __syncthreads();
        use_prev = s_stop[0];
    }

    // ---- out[b][k][w]: owned (row q*8+bo, cols ko, ko+1) ----
    #pragma unroll
    for (int j = 0; j < 2; ++j)
        out[((size_t)(q * RPB + bo) * NB + ko + j) * NW + w] =
            use_prev ? cfp[j] : cf[j];
}

// ---------------------------------------------------------------------------
extern "C" void kernel_launch(void* const* d_in, const int* in_sizes, int n_in,
                              void* d_out, int out_size, void* d_ws, size_t ws_size,
                              hipStream_t stream)
{
    const float* spec   = (const float*)d_in[0];
    const float* basis  = (const float*)d_in[1];
    const int* p_niter  = (const int*)d_in[2];
    const int* p_pad    = (const int*)d_in[3];
    const int* p_stride = (const int*)d_in[4];
    float* out = (float*)d_out;

    char* ws = (char*)d_ws;
    float*        G     = (float*)ws;                         // 256 KB
    double*       sxbuf = (double*)(ws + 262144);             // 2016 B (pad 4 KB)
    double*       gpart = (double*)(ws + 266240);             // 193536 B
    unsigned int* gcnt  = (unsigned int*)(ws + 266240 + 193536); // (MAXIT*NW+1)*4

    hipMemsetAsync(gcnt, 0, (MAXIT * NW + 1) * sizeof(unsigned int), stream);
    window_kernel<<<dim3(GRID), dim3(1024), 0, stream>>>(
        spec, basis, G, p_niter, p_pad, p_stride, sxbuf, gpart, gcnt, out);
}

// Round 13
// 287.530 us; speedup vs baseline: 1.2790x; 1.2790x over previous
//
#include <hip/hip_runtime.h>
#include <math.h>

// SparseCoding, round 13.
// Base = R10 (best, 312 us). Two isolated changes:
//  (a) fast Adam: v_rcp_f32 / v_sqrt_f32 instead of 4 precise-div sequences
//      (~80 instr + ~400 cyc dependent latency per thread/iter).
//  (b) tid64's lag-2 consume moved AFTER the GEMM writes (R9 position): its
//      acquire+L2 reads overlap sibling waves' GEMM instead of delaying wave-1's
//      GEMM start (R10 ran it at loop top -> ~0.2 us/iter barrier skew).
// Everything else (ownership GEMM, scalar fma, dual-parity exchange, 1 barrier/
// iter, lag-2 sync, last-man-out post, XCD colocation) identical to R10.
#define NB     256
#define NF     128
#define FT     1024
#define NW     63
#define TORIG  256
#define MAXIT  48
#define RPB    8
#define NBLK   4
#define GRID   256           // XCD-swizzled; 4 blocks decode w==63: gram+exit

__device__ __forceinline__ float rl(float v, int lane) {
    return __uint_as_float((unsigned)__builtin_amdgcn_readlane((int)__float_as_uint(v), lane));
}

// exchange layout (float4 index): k2*512 + row*64 + (cg ^ row)
__device__ __forceinline__ int xidx(int k2, int cg, int row) {
    return (k2 * 512 + row * 64 + (cg ^ row)) * 4;
}

__global__ __launch_bounds__(512, 2) void window_kernel(
    const float* __restrict__ spec,
    const float* __restrict__ basis,
    float* __restrict__ G,               // ws: 256x256
    const int* __restrict__ p_niter,
    const int* __restrict__ p_pad,
    const int* __restrict__ p_stride,
    double* __restrict__ sxbuf,          // [NW][NBLK]
    double* __restrict__ gpart,          // [MAXIT][NW][NBLK][2]
    unsigned int* __restrict__ gcnt,     // [MAXIT*NW] arrivals + [MAXIT*NW]=gbar (memset 0)
    float* __restrict__ out)             // (32,256,63)
{
    __shared__ float  s_p0[RPB * 2048];        // 64 KB parity-0 exchange
    __shared__ float  s_p1[RPB * 2048];        // 64 KB parity-1; head doubles as s_xn
    __shared__ float  s_gred[2][NB];
    __shared__ float  s_mn[RPB], s_rng[RPB];
    __shared__ double s_dred[8];
    __shared__ float  s_redq[2][8], s_redr[2][8];
    __shared__ unsigned int s_wcnt[2];
    __shared__ int    s_stop[2];
    float* const s_xn = s_p1;                  // setup only

    const int bid = blockIdx.x;
    const int yy  = bid >> 3;
    const int q   = yy & 3;
    const int w   = (bid & 7) + 8 * (yy >> 2);   // 4 blocks/window share bid%8 (XCD)
    const int tid = threadIdx.x;
    const int ks  = tid >> 6;                    // wave: K-slice [32ks,32ks+32)
    const int kg  = tid & 63;
    const int r   = kg >> 3;                     // owned local row
    const int cgo = 8 * ks + (kg & 7);           // owned colgroup (cols 4cgo..4cgo+3)
    const int n_iter = p_niter[0];
    const int t0     = w * p_stride[0] - p_pad[0];
    unsigned int* gbar = gcnt + MAXIT * NW;

    // ================= fused Gram: block bid computes G row bid ==================
    {
        const int c = tid & 255, jh = tid >> 8;
        float acc = 0.f;
        const float* bp = basis + (size_t)(jh * 512) * NB;
        #pragma unroll 16
        for (int j = 0; j < 512; ++j)
            acc = fmaf(bp[j * NB + bid], bp[j * NB + c], acc);
        s_gred[jh][c] = acc;
        __syncthreads();
        if (jh == 0) G[(size_t)bid * NB + c] = s_gred[0][c] + s_gred[1][c];
    }
    __threadfence();
    __syncthreads();
    if (tid == 0) atomicAdd(gbar, 1u);
    if (w >= NW) return;

    // ================= stage raw window, min/max, normalize ======================
    #pragma unroll
    for (int i = 0; i < 16; ++i) {
        const int e = i * 512 + tid;
        const int b = e >> 10, jj = e & 1023;
        const int f = jj >> 3, t = jj & 7, tq = t0 + t;
        s_xn[b * FT + jj] = (tq >= 0 && tq < TORIG)
            ? spec[((size_t)(q * RPB + b) * NF + f) * TORIG + tq] : 0.f;
    }
    __syncthreads();
    {   // wave ks scans row ks
        float mn = __builtin_inff(), mx = -__builtin_inff();
        #pragma unroll
        for (int i = 0; i < 16; ++i) {
            const float v = s_xn[ks * FT + i * 64 + kg];
            mn = fminf(mn, v); mx = fmaxf(mx, v);
        }
        #pragma unroll
        for (int off = 32; off; off >>= 1) {
            mn = fminf(mn, __shfl_down(mn, off));
            mx = fmaxf(mx, __shfl_down(mx, off));
        }
        if (kg == 0) { s_mn[ks] = mn; s_rng[ks] = mx - mn; }
    }
    __syncthreads();
    double sx2p = 0.0;
    #pragma unroll
    for (int i = 0; i < 16; ++i) {
        const int e = i * 512 + tid;
        const int b = e >> 10, jj = e & 1023;
        const float v = (s_xn[b * FT + jj] - s_mn[b]) / s_rng[b];
        s_xn[b * FT + jj] = v;
        sx2p += (double)v * (double)v;
    }
    #pragma unroll
    for (int off = 32; off; off >>= 1) sx2p += __shfl_down(sx2p, off);
    if (kg == 0) s_dred[ks] = sx2p;
    __syncthreads();
    if (tid == 0) {
        double s = 0.0;
        #pragma unroll
        for (int i = 0; i < 8; ++i) s += s_dred[i];
        sxbuf[w * NBLK + q] = s;
        __threadfence();
    }

    // ================= xB = xnorm @ basis (K-split partials into s_p0) ===========
    float xbp[RPB][4];
    #pragma unroll
    for (int b = 0; b < RPB; ++b)
        #pragma unroll
        for (int j = 0; j < 4; ++j) xbp[b][j] = 0.f;
    for (int i0 = 0; i0 < 128; i0 += 4) {
        const int jj = ks * 128 + i0;
        float4 bv[4];
        #pragma unroll
        for (int t = 0; t < 4; ++t)
            bv[t] = *(const float4*)(basis + (size_t)(jj + t) * NB + 4 * kg);
        #pragma unroll
        for (int b = 0; b < RPB; ++b) {
            const float4 x4 = *(const float4*)&s_xn[b * FT + jj];
            xbp[b][0] = fmaf(x4.x, bv[0].x, fmaf(x4.y, bv[1].x, fmaf(x4.z, bv[2].x, fmaf(x4.w, bv[3].x, xbp[b][0]))));
            xbp[b][1] = fmaf(x4.x, bv[0].y, fmaf(x4.y, bv[1].y, fmaf(x4.z, bv[2].y, fmaf(x4.w, bv[3].y, xbp[b][1]))));
            xbp[b][2] = fmaf(x4.x, bv[0].z, fmaf(x4.y, bv[1].z, fmaf(x4.z, bv[2].z, fmaf(x4.w, bv[3].z, xbp[b][2]))));
            xbp[b][3] = fmaf(x4.x, bv[0].w, fmaf(x4.y, bv[1].w, fmaf(x4.z, bv[2].w, fmaf(x4.w, bv[3].w, xbp[b][3]))));
        }
    }
    __syncthreads();
    #pragma unroll
    for (int b = 0; b < RPB; ++b)
        *(float4*)&s_p0[xidx(ks, kg, b)] =
            make_float4(xbp[b][0], xbp[b][1], xbp[b][2], xbp[b][3]);
    __syncthreads();
    float xB[4] = {0.f, 0.f, 0.f, 0.f};
    #pragma unroll
    for (int k2 = 0; k2 < 8; ++k2) {
        const float4 p4 = *(const float4*)&s_p0[xidx(k2, cgo, r)];
        xB[0] += p4.x; xB[1] += p4.y; xB[2] += p4.z; xB[3] += p4.w;
    }

    // ================= wait for G, load register fragment ========================
    if (tid == 0) {
        while (__hip_atomic_load(gbar, __ATOMIC_ACQUIRE, __HIP_MEMORY_SCOPE_AGENT) < (unsigned)GRID)
            __builtin_amdgcn_s_sleep(1);
    }
    if (tid == 64) { s_wcnt[0] = 0; s_wcnt[1] = 0; s_stop[0] = 0; s_stop[1] = 0; }
    __syncthreads();
    float4 g[32];
    #pragma unroll
    for (int kl = 0; kl < 32; ++kl)
        g[kl] = *(const float4*)(G + (size_t)(32 * ks + kl) * NB + 4 * kg);

    // ================= init owned coef / Adam ====================================
    const float C0 = 0.5f / 256.f;
    float cf[4]  = {C0, C0, C0, C0}, cfp[4] = {C0, C0, C0, C0};
    float m_[4]  = {0, 0, 0, 0},    v_[4]  = {0, 0, 0, 0};
    float b1p = 1.f, b2p = 1.f;
    float old_loss = 1e-10f;      // tid64 only
    double sxtot = 0.0;           // tid64 only
    const float c1 = 2.f / 32768.f, c2 = 0.2f / 8192.f;
    int use_prev = 0;

    for (int it = 0; it < n_iter; ++it) {
        const int p = it & 1;
        float* const sp = p ? s_p1 : s_p0;

        // ---- GEMM, b outer (scalar fma; clean SGPR x VGPR operands) ----
        #pragma unroll
        for (int b = 0; b < RPB; ++b) {
            float p0 = 0.f, p1 = 0.f, p2 = 0.f, p3 = 0.f;
            #pragma unroll
            for (int m = 0; m < 8; ++m) {
                const float4 ga = g[4 * m + 0], gb = g[4 * m + 1];
                const float4 gc = g[4 * m + 2], gd = g[4 * m + 3];
                const int L = b * 8 + m;     // lane owning coef[b][32ks+4m..+3]
                const float cx = rl(cf[0], L), cy = rl(cf[1], L);
                const float cz = rl(cf[2], L), cw = rl(cf[3], L);
                p0 = fmaf(cx, ga.x, fmaf(cy, gb.x, fmaf(cz, gc.x, fmaf(cw, gd.x, p0))));
                p1 = fmaf(cx, ga.y, fmaf(cy, gb.y, fmaf(cz, gc.y, fmaf(cw, gd.y, p1))));
                p2 = fmaf(cx, ga.z, fmaf(cy, gb.z, fmaf(cz, gc.z, fmaf(cw, gd.z, p2))));
                p3 = fmaf(cx, ga.w, fmaf(cy, gb.w, fmaf(cz, gc.w, fmaf(cw, gd.w, p3))));
            }
            *(float4*)&sp[xidx(ks, kg, b)] = make_float4(p0, p1, p2, p3);
        }

        // ---- tid64: LAG-2 consume AFTER its GEMM (overlaps siblings' tails) ----
        if (tid == 64 && it >= 2) {
            const int itc = it - 2;
            while (__hip_atomic_load(&gcnt[itc * NW + w], __ATOMIC_ACQUIRE,
                                     __HIP_MEMORY_SCOPE_AGENT) < (unsigned)NBLK)
                __builtin_amdgcn_s_sleep(1);
            const size_t pbm = ((size_t)itc * NW + w) * NBLK;
            double Qt = 0.0, Rt = 0.0;
            #pragma unroll
            for (int i = 0; i < NBLK; ++i) {
                Qt += gpart[(pbm + i) * 2 + 0];
                Rt += gpart[(pbm + i) * 2 + 1];
            }
            if (itc == 0)
                sxtot = sxbuf[w * NBLK + 0] + sxbuf[w * NBLK + 1] +
                        sxbuf[w * NBLK + 2] + sxbuf[w * NBLK + 3];
            const float loss = (float)((Qt + sxtot) / 32768.0 + 0.2 * (Rt / 8192.0));
            const float stat = fabsf(old_loss - loss) / old_loss;
            old_loss = loss;
            s_stop[p] = (stat < 1e-3f) ? 1 : 0;
        }

        __syncthreads();          // THE barrier: sp + s_stop[p] visible

        if (s_stop[p]) { use_prev = 1; break; }   // t*=it-2 -> answer = cfp

        // ---- K-reduce at owned coords ----
        float a4[4] = {0.f, 0.f, 0.f, 0.f};
        #pragma unroll
        for (int k2 = 0; k2 < 8; ++k2) {
            const float4 p4 = *(const float4*)&sp[xidx(k2, cgo, r)];
            a4[0] += p4.x; a4[1] += p4.y; a4[2] += p4.z; a4[3] += p4.w;
        }

        // ---- loss partials + last-man-out block post (skip on final iter) ----
        if (it + 1 < n_iter) {
            float qc = 0.f, rr = 0.f;
            #pragma unroll
            for (int j = 0; j < 4; ++j) {
                qc += cf[j] * (a4[j] - 2.f * xB[j]);
                rr += fabsf(cf[j]);
            }
            #pragma unroll
            for (int off = 32; off; off >>= 1) {
                qc += __shfl_down(qc, off);
                rr += __shfl_down(rr, off);
            }
            if (kg == 0) {
                s_redq[p][ks] = qc; s_redr[p][ks] = rr;
                __threadfence_block();
                const unsigned old = __hip_atomic_fetch_add(&s_wcnt[p], 1u,
                                        __ATOMIC_ACQ_REL, __HIP_MEMORY_SCOPE_WORKGROUP);
                if (old == 7u) {
                    float Q = 0.f, R = 0.f;
                    #pragma unroll
                    for (int i = 0; i < 8; ++i) { Q += s_redq[p][i]; R += s_redr[p][i]; }
                    s_wcnt[p] = 0u;
                    const size_t pb = ((size_t)it * NW + w) * NBLK;
                    gpart[(pb + q) * 2 + 0] = (double)Q;
                    gpart[(pb + q) * 2 + 1] = (double)R;
                    __hip_atomic_fetch_add(&gcnt[it * NW + w], 1u,
                                           __ATOMIC_RELEASE, __HIP_MEMORY_SCOPE_AGENT);
                }
            }
        }

        // ---- Adam update (fast rcp/sqrt; cfp snapshot first) ----
        b1p *= 0.9f; b2p *= 0.999f;
        const float rb1 = __builtin_amdgcn_rcpf(1.f - b1p);
        const float rb2 = __builtin_amdgcn_rcpf(1.f - b2p);
        #pragma unroll
        for (int j = 0; j < 4; ++j) {
            const float c_ = cf[j];
            cfp[j] = c_;
            const float sgn = (c_ > 0.f) ? 1.f : ((c_ < 0.f) ? -1.f : 0.f);
            const float gg = c1 * (a4[j] - xB[j]) + c2 * sgn;
            m_[j] = 0.9f * m_[j] + 0.1f * gg;
            v_[j] = 0.999f * v_[j] + 0.001f * gg * gg;
            const float den = __builtin_amdgcn_sqrtf(v_[j] * rb2) + 1e-8f;
            cf[j] = c_ - 1e-3f * (m_[j] * rb1) * __builtin_amdgcn_rcpf(den);
        }
    }

    // ---- post-loop consume round: conv at t = n_iter-2 (if not already stopped) ----
    if (!use_prev && n_iter >= 2) {
        if (tid == 64) {
            const int itc = n_iter - 2;
            while (__hip_atomic_load(&gcnt[itc * NW + w], __ATOMIC_ACQUIRE,
                                     __HIP_MEMORY_SCOPE_AGENT) < (unsigned)NBLK)
                __builtin_amdgcn_s_sleep(1);
            const size_t pbm = ((size_t)itc * NW + w) * NBLK;
            double Qt = 0.0, Rt = 0.0;
            #pragma unroll
            for (int i = 0; i < NBLK; ++i) {
                Qt += gpart[(pbm + i) * 2 + 0];
                Rt += gpart[(pbm + i) * 2 + 1];
            }
            if (itc == 0)
                sxtot = sxbuf[w * NBLK + 0] + sxbuf[w * NBLK + 1] +
                        sxbuf[w * NBLK + 2] + sxbuf[w * NBLK + 3];
            const float loss = (float)((Qt + sxtot) / 32768.0 + 0.2 * (Rt / 8192.0));
            const float stat = fabsf(old_loss - loss) / old_loss;
            s_stop[0] = (stat < 1e-3f) ? 1 : 0;
        }
        __syncthreads();
        use_prev = s_stop[0];
    }

    // ---- out[b][k][w]: owned (row q*8+r, cols 4cgo..+3) ----
    #pragma unroll
    for (int j = 0; j < 4; ++j)
        out[((size_t)(q * RPB + r) * NB + 4 * cgo + j) * NW + w] =
            use_prev ? cfp[j] : cf[j];
}

// ---------------------------------------------------------------------------
extern "C" void kernel_launch(void* const* d_in, const int* in_sizes, int n_in,
                              void* d_out, int out_size, void* d_ws, size_t ws_size,
                              hipStream_t stream)
{
    const float* spec   = (const float*)d_in[0];
    const float* basis  = (const float*)d_in[1];
    const int* p_niter  = (const int*)d_in[2];
    const int* p_pad    = (const int*)d_in[3];
    const int* p_stride = (const int*)d_in[4];
    float* out = (float*)d_out;

    char* ws = (char*)d_ws;
    float*        G     = (float*)ws;                         // 256 KB
    double*       sxbuf = (double*)(ws + 262144);             // 2016 B (pad 4 KB)
    double*       gpart = (double*)(ws + 266240);             // 193536 B
    unsigned int* gcnt  = (unsigned int*)(ws + 266240 + 193536); // (MAXIT*NW+1)*4

    hipMemsetAsync(gcnt, 0, (MAXIT * NW + 1) * sizeof(unsigned int), stream);
    window_kernel<<<dim3(GRID), dim3(512), 0, stream>>>(
        spec, basis, G, p_niter, p_pad, p_stride, sxbuf, gpart, gcnt, out);
}